// Round 1
// baseline (1551.563 us; speedup 1.0000x reference)
//
#include <hip/hip_runtime.h>
#include <math.h>

#define TN   4096
#define DI   1024
#define DOUT 1024
#define BSZ  60
#define LOGT 8.317766166719343f
#define EPSV 1e-12f

// ---------------- reduction helpers (256-thread blocks, wave=64) ----------------
__device__ __forceinline__ float wsum(float v){
#pragma unroll
  for (int o = 32; o >= 1; o >>= 1) v += __shfl_xor(v, o);
  return v;
}
__device__ __forceinline__ float wmaxr(float v){
#pragma unroll
  for (int o = 32; o >= 1; o >>= 1) v = fmaxf(v, __shfl_xor(v, o));
  return v;
}
__device__ __forceinline__ float bsum(float v, float* sh){
  v = wsum(v);
  if ((threadIdx.x & 63) == 0) sh[threadIdx.x >> 6] = v;
  __syncthreads();
  float r = sh[0] + sh[1] + sh[2] + sh[3];
  __syncthreads();
  return r;
}
__device__ __forceinline__ float bmaxr(float v, float* sh){
  v = wmaxr(v);
  if ((threadIdx.x & 63) == 0) sh[threadIdx.x >> 6] = v;
  __syncthreads();
  float r = fmaxf(fmaxf(sh[0], sh[1]), fmaxf(sh[2], sh[3]));
  __syncthreads();
  return r;
}

// ---------------- 1. row L2-normalize: xu = x / max(||x||,eps) ----------------
__global__ __launch_bounds__(256) void k_rownorm(const float* __restrict__ x,
                                                 float* __restrict__ xu){
  __shared__ float sh[4];
  int r = blockIdx.x, tid = threadIdx.x;
  const float4* xr = (const float4*)(x + (size_t)r * DI);
  float4 v = xr[tid];
  float ss = v.x*v.x + v.y*v.y + v.z*v.z + v.w*v.w;
  ss = bsum(ss, sh);
  float inv = 1.f / fmaxf(sqrtf(ss), EPSV);
  float4 o = {v.x*inv, v.y*inv, v.z*inv, v.w*inv};
  ((float4*)(xu + (size_t)r * DI))[tid] = o;
}

// ---------------- 2. column sum of xu (deterministic 2-stage) ----------------
__global__ __launch_bounds__(256) void k_colsum1(const float* __restrict__ xu,
                                                 float* __restrict__ part){
  int c  = blockIdx.x * 256 + threadIdx.x;
  int r0 = blockIdx.y * 128;
  float s = 0.f;
  for (int r = r0; r < r0 + 128; ++r) s += xu[(size_t)r * DI + c];
  part[(size_t)blockIdx.y * DI + c] = s;
}
__global__ __launch_bounds__(256) void k_colsum2(const float* __restrict__ part,
                                                 float* __restrict__ stot){
  int c = blockIdx.x * 256 + threadIdx.x;
  float s = 0.f;
  for (int b = 0; b < 32; ++b) s += part[(size_t)b * DI + c];
  stot[c] = s;
}

// ---------------- 3. tiled fp32 GEMM: C[M,N] = A[M,K] @ B ----------------
// TRANSB=false: B is [K,N] row-major.  TRANSB=true: B is [N,K] row-major (C=A*B^T).
template<bool TRANSB>
__global__ __launch_bounds__(256) void k_gemm(const float* __restrict__ A,
                                              const float* __restrict__ B,
                                              float* __restrict__ C,
                                              int M, int N, int K){
  __shared__ float As[16][68];   // [k][row] (A transposed in LDS)
  __shared__ float Bs[16][68];   // [k][col]
  int row0 = blockIdx.y * 64, col0 = blockIdx.x * 64;
  int tid = threadIdx.x, tx = tid & 15, ty = tid >> 4;
  float acc[4][4] = {};
  for (int k0 = 0; k0 < K; k0 += 16){
#pragma unroll
    for (int l = 0; l < 4; ++l){
      int lin = tid + l * 256;
      int r = lin >> 4, c = lin & 15;
      As[c][r] = A[(size_t)(row0 + r) * K + k0 + c];
    }
    if (!TRANSB){
#pragma unroll
      for (int l = 0; l < 4; ++l){
        int lin = tid + l * 256;
        int r = lin >> 6, c = lin & 63;
        Bs[r][c] = B[(size_t)(k0 + r) * N + col0 + c];
      }
    } else {
#pragma unroll
      for (int l = 0; l < 4; ++l){
        int lin = tid + l * 256;
        int c = lin >> 4, r = lin & 15;
        Bs[r][c] = B[(size_t)(col0 + c) * K + k0 + r];
      }
    }
    __syncthreads();
#pragma unroll
    for (int kk = 0; kk < 16; ++kk){
      float4 a4 = *(const float4*)&As[kk][ty * 4];
      float4 b4 = *(const float4*)&Bs[kk][tx * 4];
      float av[4] = {a4.x, a4.y, a4.z, a4.w};
      float bv[4] = {b4.x, b4.y, b4.z, b4.w};
#pragma unroll
      for (int i2 = 0; i2 < 4; ++i2)
#pragma unroll
        for (int j = 0; j < 4; ++j) acc[i2][j] += av[i2] * bv[j];
    }
    __syncthreads();
  }
#pragma unroll
  for (int i2 = 0; i2 < 4; ++i2){
    size_t r = row0 + ty * 4 + i2;
    float4 o = {acc[i2][0], acc[i2][1], acc[i2][2], acc[i2][3]};
    *(float4*)&C[r * N + col0 + tx * 4] = o;
  }
}

// ---------------- 4. row stats over E; converts E -> P (softmax) in place ----------------
__global__ __launch_bounds__(256) void k_rowstats(float* __restrict__ E,
                                                  float* __restrict__ Hraw,
                                                  float* __restrict__ Hwin,
                                                  float* __restrict__ divh){
  __shared__ float sh[4];
  int i = blockIdx.x, tid = threadIdx.x;
  float4* row4 = (float4*)(E + (size_t)i * TN);
  float4 v[4];
#pragma unroll
  for (int k = 0; k < 4; ++k) v[k] = row4[tid + k * 256];

  float mx = -3.4e38f;
#pragma unroll
  for (int k = 0; k < 4; ++k)
    mx = fmaxf(mx, fmaxf(fmaxf(v[k].x, v[k].y), fmaxf(v[k].z, v[k].w)));
  mx = bmaxr(mx, sh);

  float s1 = 0.f, s2 = 0.f;
#pragma unroll
  for (int k = 0; k < 4; ++k){
    float e[4] = {v[k].x, v[k].y, v[k].z, v[k].w};
#pragma unroll
    for (int q = 0; q < 4; ++q){
      float t = e[q] - mx; float w = __expf(t); s1 += w; s2 += w * t;
    }
  }
  s1 = bsum(s1, sh);
  s2 = bsum(s2, sh);
  float rl = 1.f / s1;
  float H  = (__logf(s1) - s2 * rl) / LOGT;

  // div_h = prod(1-p) via sum of log1p; also overwrite regs with p
  float ld = 0.f;
#pragma unroll
  for (int k = 0; k < 4; ++k){
    float e[4] = {v[k].x, v[k].y, v[k].z, v[k].w};
    float p[4];
#pragma unroll
    for (int q = 0; q < 4; ++q){
      p[q] = __expf(e[q] - mx) * rl;
      ld += log1pf(-p[q]);
    }
    v[k].x = p[0]; v[k].y = p[1]; v[k].z = p[2]; v[k].w = p[3];
  }
  ld = bsum(ld, sh);

  // windowed entropy (in-block energies + (TN-nb) zeros), wave 0, raw E still in memory
  if (tid < 64){
    int b0 = (i / BSZ) * BSZ;
    int b1 = min(b0 + BSZ, TN);
    int nb = b1 - b0;
    float e = (tid < nb) ? E[(size_t)i * TN + b0 + tid] : -3.4e38f;
    float mw = wmaxr(e);
    mw = fmaxf(mw, 0.f);
    float t = e - mw;
    float w  = (tid < nb) ? __expf(t) : 0.f;
    float wt = (tid < nb) ? w * t     : 0.f;
    float z  = __expf(-mw);
    float s1w = wsum(w)  + (float)(TN - nb) * z;
    float s2w = wsum(wt) + (float)(TN - nb) * z * (-mw);
    if (tid == 0) Hwin[i] = (__logf(s1w) - s2w / s1w) / LOGT;
  }
  __syncthreads();          // raw-E readers done before overwrite
#pragma unroll
  for (int k = 0; k < 4; ++k) row4[tid + k * 256] = v[k];
  if (tid == 0){
    Hraw[i] = H;
    divh[i] = __expf(ld);
  }
}

// ---------------- 5. deterministic L1 sums of Hraw / divh ----------------
__global__ __launch_bounds__(256) void k_sumvec(const float* __restrict__ Hraw,
                                                const float* __restrict__ divh,
                                                float* __restrict__ sums){
  __shared__ float sh[4];
  int tid = threadIdx.x;
  float a = 0.f, b = 0.f;
  for (int i = tid; i < TN; i += 256){ a += fabsf(Hraw[i]); b += fabsf(divh[i]); }
  a = bsum(a, sh);
  b = bsum(b, sh);
  if (tid == 0){ sums[0] = a; sums[1] = b; }
}

__global__ __launch_bounds__(256) void k_vecnorm(const float* __restrict__ Hraw,
                                                 const float* __restrict__ divh,
                                                 const float* __restrict__ sums,
                                                 float* __restrict__ entn,
                                                 float* __restrict__ divn){
  int i = blockIdx.x * 256 + threadIdx.x;
  if (i < TN){
    entn[i] = Hraw[i] / fmaxf(sums[0], EPSV);
    divn[i] = divh[i] / sums[1];      // reference has no eps guard here
  }
}

// ---------------- 6. dep_factor per row ----------------
// num = (1 - sum_in att) - (xi.c_i - sum_in att*sim)
// den = (TN - nb)        - (xi.stot - sum_in sim)
__global__ __launch_bounds__(256) void k_dep(const float* __restrict__ xu,
                                             const float* __restrict__ stot,
                                             const float* __restrict__ cb,
                                             const float* __restrict__ P,
                                             float* __restrict__ dep){
  __shared__ float xi[DI];
  __shared__ float sh[4];
  __shared__ float accs[4][3];
  int i = blockIdx.x, tid = threadIdx.x;
  float4 v = ((const float4*)(xu + (size_t)i * DI))[tid];
  ((float4*)xi)[tid] = v;
  float4 s4 = ((const float4*)stot)[tid];
  float4 c4 = ((const float4*)(cb + (size_t)i * DI))[tid];
  float pa = v.x*s4.x + v.y*s4.y + v.z*s4.z + v.w*s4.w;
  float pb = v.x*c4.x + v.y*c4.y + v.z*c4.z + v.w*c4.w;
  float sim_all    = bsum(pa, sh);   // also fences xi writes
  float simatt_all = bsum(pb, sh);

  int b0 = (i / BSZ) * BSZ;
  int b1 = min(b0 + BSZ, TN);
  int nb = b1 - b0;
  int wid = tid >> 6, lane = tid & 63;
  float att_in = 0.f, sim_in = 0.f, simatt_in = 0.f;
  for (int j = b0 + wid; j < b1; j += 4){
    const float* xj = xu + (size_t)j * DI;
    float s = 0.f;
#pragma unroll
    for (int d = 0; d < 16; ++d) s += xi[d * 64 + lane] * xj[d * 64 + lane];
#pragma unroll
    for (int o = 32; o >= 1; o >>= 1) s += __shfl_xor(s, o);   // all lanes get sim
    float att = P[(size_t)i * TN + j];
    att_in += att; sim_in += s; simatt_in += att * s;
  }
  if (lane == 0){ accs[wid][0] = att_in; accs[wid][1] = sim_in; accs[wid][2] = simatt_in; }
  __syncthreads();
  if (tid == 0){
    float a = 0.f, si = 0.f, sa = 0.f;
#pragma unroll
    for (int w = 0; w < 4; ++w){ a += accs[w][0]; si += accs[w][1]; sa += accs[w][2]; }
    float num = (1.f - a) - (simatt_all - sa);
    float den = (float)(TN - nb) - (sim_all - si);
    dep[i] = num / den;
  }
}

// ---------------- 7. y_mid[i] = sum_{j in blk} (P[i,j]+dep[j]) * V[j] ----------------
__global__ __launch_bounds__(256) void k_ymid(const float* __restrict__ P,
                                              const float* __restrict__ dep,
                                              const float* __restrict__ V,
                                              float* __restrict__ ym){
  __shared__ float w[64];
  int i = blockIdx.x, tid = threadIdx.x;
  int b0 = (i / BSZ) * BSZ;
  int b1 = min(b0 + BSZ, TN);
  int nb = b1 - b0;
  if (tid < nb) w[tid] = P[(size_t)i * TN + b0 + tid] + dep[b0 + tid];
  __syncthreads();
  float4 acc = {0.f, 0.f, 0.f, 0.f};
  for (int jj = 0; jj < nb; ++jj){
    float wv = w[jj];
    float4 vv = ((const float4*)(V + (size_t)(b0 + jj) * DI))[tid];
    acc.x += wv * vv.x; acc.y += wv * vv.y; acc.z += wv * vv.z; acc.w += wv * vv.w;
  }
  ((float4*)(ym + (size_t)i * DI))[tid] = acc;
}

// ---------------- 8. final GEMM + rank-2 epilogue ----------------
// C = ym @ Wout[0:DOUT] + entn[i]*Wout[DOUT] + dep[i]*Wout[DOUT+1]
__global__ __launch_bounds__(256) void k_gemm_final(const float* __restrict__ A,
                                                    const float* __restrict__ W,
                                                    float* __restrict__ C,
                                                    const float* __restrict__ entn,
                                                    const float* __restrict__ dep){
  __shared__ float As[16][68];
  __shared__ float Bs[16][68];
  int row0 = blockIdx.y * 64, col0 = blockIdx.x * 64;
  int tid = threadIdx.x, tx = tid & 15, ty = tid >> 4;
  float acc[4][4] = {};
  for (int k0 = 0; k0 < DOUT; k0 += 16){
#pragma unroll
    for (int l = 0; l < 4; ++l){
      int lin = tid + l * 256;
      int r = lin >> 4, c = lin & 15;
      As[c][r] = A[(size_t)(row0 + r) * DOUT + k0 + c];
    }
#pragma unroll
    for (int l = 0; l < 4; ++l){
      int lin = tid + l * 256;
      int r = lin >> 6, c = lin & 63;
      Bs[r][c] = W[(size_t)(k0 + r) * DI + col0 + c];
    }
    __syncthreads();
#pragma unroll
    for (int kk = 0; kk < 16; ++kk){
      float4 a4 = *(const float4*)&As[kk][ty * 4];
      float4 b4 = *(const float4*)&Bs[kk][tx * 4];
      float av[4] = {a4.x, a4.y, a4.z, a4.w};
      float bv[4] = {b4.x, b4.y, b4.z, b4.w};
#pragma unroll
      for (int i2 = 0; i2 < 4; ++i2)
#pragma unroll
        for (int j = 0; j < 4; ++j) acc[i2][j] += av[i2] * bv[j];
    }
    __syncthreads();
  }
  const float* w1 = W + (size_t)DOUT * DI;
  const float* w2 = W + (size_t)(DOUT + 1) * DI;
#pragma unroll
  for (int i2 = 0; i2 < 4; ++i2){
    size_t r = row0 + ty * 4 + i2;
    float en = entn[r], dp = dep[r];
    float4 o;
    int c = col0 + tx * 4;
    o.x = acc[i2][0] + en * w1[c+0] + dp * w2[c+0];
    o.y = acc[i2][1] + en * w1[c+1] + dp * w2[c+1];
    o.z = acc[i2][2] + en * w1[c+2] + dp * w2[c+2];
    o.w = acc[i2][3] + en * w1[c+3] + dp * w2[c+3];
    *(float4*)&C[r * DI + c] = o;
  }
}

// ---------------- 9. fill att_win / ent_win / div_win outputs ----------------
// att_out aliases P (in-place): each thread reads its own P floats before storing.
__global__ __launch_bounds__(256) void k_fill(const float* __restrict__ P,
                                              const float* __restrict__ dep,
                                              const float* __restrict__ Hwin,
                                              const float* __restrict__ divn,
                                              float* att_o,
                                              float* __restrict__ ent_o,
                                              float* __restrict__ div_o){
  int i  = blockIdx.y;
  int j4 = (blockIdx.x * 256 + threadIdx.x) * 4;
  size_t base = (size_t)i * TN + j4;
  float4 hv = *(const float4*)(Hwin + j4);
  float4 dv = *(const float4*)(divn + j4);
  *(float4*)(ent_o + base) = hv;
  *(float4*)(div_o + base) = dv;

  int blk = i / BSZ;
  int b0 = blk * BSZ;
  int b1 = min(b0 + BSZ, TN);
  float4 av = {0.f, 0.f, 0.f, 0.f};
  if (j4 + 3 >= b0 && j4 < b1){
    float t[4];
#pragma unroll
    for (int q = 0; q < 4; ++q){
      int j = j4 + q;
      t[q] = (j >= b0 && j < b1) ? (P[base + q] + dep[j]) : 0.f;
    }
    av.x = t[0]; av.y = t[1]; av.z = t[2]; av.w = t[3];
  }
  *(float4*)(att_o + base) = av;
}

// ---------------- launcher ----------------
extern "C" void kernel_launch(void* const* d_in, const int* in_sizes, int n_in,
                              void* d_out, int out_size, void* d_ws, size_t ws_size,
                              hipStream_t stream){
  const float* x    = (const float*)d_in[0];
  const float* Wk   = (const float*)d_in[1];
  const float* Wq   = (const float*)d_in[2];
  const float* Wv   = (const float*)d_in[3];
  const float* Wout = (const float*)d_in[4];

  float* out     = (float*)d_out;
  float* y_out   = out;                              // TN*DI
  float* att_out = out + (size_t)TN * DI;            // TN*TN
  float* ent_out = att_out + (size_t)TN * TN;        // TN*TN
  float* div_out = ent_out + (size_t)TN * TN;        // TN*TN
  float* E = att_out;                                // E/P scratch lives in att output

  float* ws = (float*)d_ws;
  // small vectors always in ws (~234 KB)
  float* Hraw = ws;
  float* Hw   = Hraw + TN;
  float* divh = Hw + TN;
  float* dep  = divh + TN;
  float* entn = dep + TN;
  float* divn = entn + TN;
  float* part = divn + TN;          // 32*DI
  float* stot = part + 32 * DI;     // DI
  float* sums = stot + DI;          // 2

  // big buffers: 16M floats (xu,Q,K,V). Use ws if it fits, else ent_win region.
  size_t big_need_bytes = ((size_t)65536 + (size_t)4 * TN * DI) * sizeof(float);
  float* big = (ws_size >= big_need_bytes) ? (ws + 65536) : ent_out;
  float* xu = big;
  float* Qb = xu + (size_t)TN * DI;   // later: c = P @ xu
  float* Kb = Qb + (size_t)TN * DI;   // later: y_mid
  float* Vb = Kb + (size_t)TN * DI;

  k_rownorm<<<dim3(TN), 256, 0, stream>>>(x, xu);
  k_colsum1<<<dim3(4, 32), 256, 0, stream>>>(xu, part);
  k_colsum2<<<dim3(4), 256, 0, stream>>>(part, stot);

  k_gemm<false><<<dim3(DOUT/64, TN/64), 256, 0, stream>>>(x, Wq, Qb, TN, DOUT, DI);
  k_gemm<false><<<dim3(DOUT/64, TN/64), 256, 0, stream>>>(x, Wk, Kb, TN, DOUT, DI);
  k_gemm<false><<<dim3(DOUT/64, TN/64), 256, 0, stream>>>(x, Wv, Vb, TN, DOUT, DI);

  k_gemm<true><<<dim3(TN/64, TN/64), 256, 0, stream>>>(Qb, Kb, E, TN, TN, DOUT);

  k_rowstats<<<dim3(TN), 256, 0, stream>>>(E, Hraw, Hw, divh);   // E -> P in place
  k_sumvec<<<dim3(1), 256, 0, stream>>>(Hraw, divh, sums);
  k_vecnorm<<<dim3(16), 256, 0, stream>>>(Hraw, divh, sums, entn, divn);

  k_gemm<false><<<dim3(DI/64, TN/64), 256, 0, stream>>>(E, xu, Qb, TN, DI, TN); // c = P@xu

  k_dep<<<dim3(TN), 256, 0, stream>>>(xu, stot, Qb, E, dep);
  k_ymid<<<dim3(TN), 256, 0, stream>>>(E, dep, Vb, Kb);
  k_gemm_final<<<dim3(DI/64, TN/64), 256, 0, stream>>>(Kb, Wout, y_out, entn, dep);
  k_fill<<<dim3(4, TN), 256, 0, stream>>>(E, dep, Hw, divn, att_out, ent_out, div_out);
}

// Round 3
// 555.223 us; speedup vs baseline: 2.7945x; 2.7945x over previous
//
#include <hip/hip_runtime.h>
#include <math.h>
#include <stdint.h>

#define TN   4096
#define DI   1024
#define BSZ  60
#define LOGT 8.317766166719343f
#define EPSV 1e-12f

typedef __bf16 bf16;
typedef bf16  bf16x4 __attribute__((ext_vector_type(4)));
typedef bf16  bf16x8 __attribute__((ext_vector_type(8)));
typedef float f32x4  __attribute__((ext_vector_type(4)));

#define AS1 __attribute__((address_space(1)))
#define AS3 __attribute__((address_space(3)))

__device__ __forceinline__ void gload16(const void* g, void* l){
  __builtin_amdgcn_global_load_lds((AS1 unsigned int*)(uintptr_t)g,
                                   (AS3 unsigned int*)(unsigned int)(uintptr_t)l,
                                   16, 0, 0);
}

// ---------------- reductions ----------------
__device__ __forceinline__ float wsum(float v){
#pragma unroll
  for (int o = 32; o >= 1; o >>= 1) v += __shfl_xor(v, o);
  return v;
}
__device__ __forceinline__ float wmaxr(float v){
#pragma unroll
  for (int o = 32; o >= 1; o >>= 1) v = fmaxf(v, __shfl_xor(v, o));
  return v;
}
__device__ __forceinline__ float bsum(float v, float* sh){
  v = wsum(v);
  if ((threadIdx.x & 63) == 0) sh[threadIdx.x >> 6] = v;
  __syncthreads();
  float r = sh[0] + sh[1] + sh[2] + sh[3];
  __syncthreads();
  return r;
}
__device__ __forceinline__ float bmaxr(float v, float* sh){
  v = wmaxr(v);
  if ((threadIdx.x & 63) == 0) sh[threadIdx.x >> 6] = v;
  __syncthreads();
  float r = fmaxf(fmaxf(sh[0], sh[1]), fmaxf(sh[2], sh[3]));
  __syncthreads();
  return r;
}

// ---------------- split fp32 -> bf16 hi/lo ----------------
__global__ __launch_bounds__(256) void k_split(const float* __restrict__ in,
                                               bf16* __restrict__ hi,
                                               bf16* __restrict__ lo){
  int idx = blockIdx.x * 256 + threadIdx.x;
  float4 v = ((const float4*)in)[idx];
  bf16 h0 = (bf16)v.x, h1 = (bf16)v.y, h2 = (bf16)v.z, h3 = (bf16)v.w;
  bf16x4 hv = {h0, h1, h2, h3};
  bf16x4 lv = {(bf16)(v.x - (float)h0), (bf16)(v.y - (float)h1),
               (bf16)(v.z - (float)h2), (bf16)(v.w - (float)h3)};
  ((bf16x4*)hi)[idx] = hv;
  ((bf16x4*)lo)[idx] = lv;
}

// ---------------- row L2-normalize ----------------
__global__ __launch_bounds__(256) void k_rownorm(const float* __restrict__ x,
                                                 float* __restrict__ xu){
  __shared__ float sh[4];
  int r = blockIdx.x, tid = threadIdx.x;
  float4 v = ((const float4*)(x + (size_t)r * DI))[tid];
  float ss = v.x*v.x + v.y*v.y + v.z*v.z + v.w*v.w;
  ss = bsum(ss, sh);
  float inv = 1.f / fmaxf(sqrtf(ss), EPSV);
  float4 o = {v.x*inv, v.y*inv, v.z*inv, v.w*inv};
  ((float4*)(xu + (size_t)r * DI))[tid] = o;
}

// ---------------- transpose fp32 [R][C] -> bf16 [C][R] (hi, optional lo) ----------------
template<bool LO>
__global__ __launch_bounds__(256) void k_tr(const float* __restrict__ in,
                                            bf16* __restrict__ outh,
                                            bf16* __restrict__ outl,
                                            int R, int C){
  __shared__ float t[64][65];
  int c0 = blockIdx.x * 64, r0 = blockIdx.y * 64;
  int tid = threadIdx.x;
  int lr = tid >> 4, lc = (tid & 15) * 4;
#pragma unroll
  for (int p = 0; p < 4; ++p){
    int r = lr + p * 16;
    float4 v = *(const float4*)&in[(size_t)(r0 + r) * C + c0 + lc];
    t[r][lc+0] = v.x; t[r][lc+1] = v.y; t[r][lc+2] = v.z; t[r][lc+3] = v.w;
  }
  __syncthreads();
#pragma unroll
  for (int p = 0; p < 4; ++p){
    int c = lr + p * 16;
    float v0 = t[lc+0][c], v1 = t[lc+1][c], v2 = t[lc+2][c], v3 = t[lc+3][c];
    bf16 h0 = (bf16)v0, h1 = (bf16)v1, h2 = (bf16)v2, h3 = (bf16)v3;
    bf16x4 hv = {h0, h1, h2, h3};
    *(bf16x4*)&outh[(size_t)(c0 + c) * R + r0 + lc] = hv;
    if (LO){
      bf16x4 lv = {(bf16)(v0-(float)h0), (bf16)(v1-(float)h1),
                   (bf16)(v2-(float)h2), (bf16)(v3-(float)h3)};
      *(bf16x4*)&outl[(size_t)(c0 + c) * R + r0 + lc] = lv;
    }
  }
}

// ---------------- column sums of xu ----------------
__global__ __launch_bounds__(256) void k_colsum1(const float* __restrict__ xu,
                                                 float* __restrict__ part){
  int c  = blockIdx.x * 256 + threadIdx.x;
  int r0 = blockIdx.y * 128;
  float s = 0.f;
  for (int r = r0; r < r0 + 128; ++r) s += xu[(size_t)r * DI + c];
  part[(size_t)blockIdx.y * DI + c] = s;
}
__global__ __launch_bounds__(256) void k_colsum2(const float* __restrict__ part,
                                                 float* __restrict__ stot){
  int c = blockIdx.x * 256 + threadIdx.x;
  float s = 0.f;
  for (int b = 0; b < 32; ++b) s += part[(size_t)b * DI + c];
  stot[c] = s;
}

// ---------------- MFMA GEMM: C[M,N] = A[M,K] * Bt[N,K]^T ----------------
// SPLIT: 1 = plain (Ah*Bh), 3 = hi/lo 3-pass.
// EPI: 0 = fp32 C;  1 = bf16 hi/lo pair;  2 = fp32 C + ev[row]*W12[col] + dv[row]*W12[DI+col]
template<int SPLIT, int EPI>
__global__ __launch_bounds__(256) void k_mfma(
    const bf16* __restrict__ Ah, const bf16* __restrict__ Al,
    const bf16* __restrict__ Bh, const bf16* __restrict__ Bl,
    int lda, int ldb, int N, int K,
    float* __restrict__ C, bf16* __restrict__ Chi, bf16* __restrict__ Clo,
    const float* __restrict__ ev, const float* __restrict__ dv,
    const float* __restrict__ W12)
{
  constexpr int NT = (SPLIT == 3) ? 4 : 2;
  __shared__ alignas(16) bf16 lds[NT * 4096];
  bf16* sAh = lds;
  bf16* sBh = lds + 4096;
  bf16* sAl = lds + 8192;
  bf16* sBl = lds + 12288;

  const int tid = threadIdx.x;
  const int wid = tid >> 6;
  const int lane = tid & 63;
  const int row0 = blockIdx.y * 128, col0 = blockIdx.x * 128;
  const int wr = (wid >> 1) * 64, wc = (wid & 1) * 64;
  const int l15 = lane & 15, kb = lane >> 4;

  // staging: unit u (0..511) = 16B; row=u>>2, slot=u&3, src koff = slot ^ ((row>>1)&3)
  const int u0 = tid,       r0u = u0 >> 2, k0u = (u0 & 3) ^ ((r0u >> 1) & 3);
  const int u1 = tid + 256, r1u = u1 >> 2, k1u = (u1 & 3) ^ ((r1u >> 1) & 3);
  const int d0 = wid * 64 * 8;
  const int d1 = (256 + wid * 64) * 8;

  f32x4 acc[4][4];
  const f32x4 zero = {0.f, 0.f, 0.f, 0.f};
#pragma unroll
  for (int m = 0; m < 4; ++m)
#pragma unroll
    for (int n = 0; n < 4; ++n) acc[m][n] = zero;

  const bf16* pAh = Ah + (size_t)row0 * lda;
  const bf16* pBh = Bh + (size_t)col0 * ldb;
  const bf16* pAl = (SPLIT == 3) ? Al + (size_t)row0 * lda : nullptr;
  const bf16* pBl = (SPLIT == 3) ? Bl + (size_t)col0 * ldb : nullptr;

  for (int k0 = 0; k0 < K; k0 += 32){
    gload16(pAh + k0 + (size_t)r0u * lda + k0u * 8, sAh + d0);
    gload16(pAh + k0 + (size_t)r1u * lda + k1u * 8, sAh + d1);
    gload16(pBh + k0 + (size_t)r0u * ldb + k0u * 8, sBh + d0);
    gload16(pBh + k0 + (size_t)r1u * ldb + k1u * 8, sBh + d1);
    if constexpr (SPLIT == 3){
      gload16(pAl + k0 + (size_t)r0u * lda + k0u * 8, sAl + d0);
      gload16(pAl + k0 + (size_t)r1u * lda + k1u * 8, sAl + d1);
      gload16(pBl + k0 + (size_t)r0u * ldb + k0u * 8, sBl + d0);
      gload16(pBl + k0 + (size_t)r1u * ldb + k1u * 8, sBl + d1);
    }
    __syncthreads();

    bf16x8 bh[4], bl2[4];
#pragma unroll
    for (int n = 0; n < 4; ++n){
      int rr = wc + n * 16 + l15;
      int ss = kb ^ ((rr >> 1) & 3);
      bh[n] = *(const bf16x8*)(sBh + (rr * 4 + ss) * 8);
      if constexpr (SPLIT == 3) bl2[n] = *(const bf16x8*)(sBl + (rr * 4 + ss) * 8);
    }
#pragma unroll
    for (int m = 0; m < 4; ++m){
      int rr = wr + m * 16 + l15;
      int ss = kb ^ ((rr >> 1) & 3);
      bf16x8 ah = *(const bf16x8*)(sAh + (rr * 4 + ss) * 8);
      bf16x8 al2;
      if constexpr (SPLIT == 3) al2 = *(const bf16x8*)(sAl + (rr * 4 + ss) * 8);
#pragma unroll
      for (int n = 0; n < 4; ++n){
        acc[m][n] = __builtin_amdgcn_mfma_f32_16x16x32_bf16(ah, bh[n], acc[m][n], 0, 0, 0);
        if constexpr (SPLIT == 3){
          acc[m][n] = __builtin_amdgcn_mfma_f32_16x16x32_bf16(ah, bl2[n], acc[m][n], 0, 0, 0);
          acc[m][n] = __builtin_amdgcn_mfma_f32_16x16x32_bf16(al2, bh[n], acc[m][n], 0, 0, 0);
        }
      }
    }
    __syncthreads();
  }

  const int l4 = lane >> 4;
#pragma unroll
  for (int m = 0; m < 4; ++m){
#pragma unroll
    for (int n = 0; n < 4; ++n){
#pragma unroll
      for (int r = 0; r < 4; ++r){
        int row = row0 + wr + m * 16 + l4 * 4 + r;
        int col = col0 + wc + n * 16 + l15;
        float v = acc[m][n][r];
        if constexpr (EPI == 0){
          C[(size_t)row * N + col] = v;
        } else if constexpr (EPI == 1){
          bf16 h = (bf16)v;
          Chi[(size_t)row * N + col] = h;
          Clo[(size_t)row * N + col] = (bf16)(v - (float)h);
        } else {
          v += ev[row] * W12[col] + dv[row] * W12[DI + col];
          C[(size_t)row * N + col] = v;
        }
      }
    }
  }
}

// ---------------- row stats over E; writes P (bf16) to a SEPARATE region ----------------
__global__ __launch_bounds__(256) void k_rowstats(const float* __restrict__ E,
                                                  bf16* __restrict__ Pbf,
                                                  float* __restrict__ Hraw,
                                                  float* __restrict__ Hwin,
                                                  float* __restrict__ divh){
  __shared__ float sh[4];
  int i = blockIdx.x, tid = threadIdx.x;
  const float4* row4 = (const float4*)(E + (size_t)i * TN);
  float4 v[4];
#pragma unroll
  for (int k = 0; k < 4; ++k) v[k] = row4[tid + k * 256];

  int b0 = (i / BSZ) * BSZ;
  int b1 = min(b0 + BSZ, TN);
  int nb = b1 - b0;
  float ewin = -3.4e38f;
  if (tid < 64 && tid < nb) ewin = E[(size_t)i * TN + b0 + tid];

  float mx = -3.4e38f;
#pragma unroll
  for (int k = 0; k < 4; ++k)
    mx = fmaxf(mx, fmaxf(fmaxf(v[k].x, v[k].y), fmaxf(v[k].z, v[k].w)));
  mx = bmaxr(mx, sh);

  float s1 = 0.f, s2 = 0.f;
#pragma unroll
  for (int k = 0; k < 4; ++k){
    float e[4] = {v[k].x, v[k].y, v[k].z, v[k].w};
#pragma unroll
    for (int q = 0; q < 4; ++q){
      float t = e[q] - mx; float w = __expf(t); s1 += w; s2 += w * t;
    }
  }
  s1 = bsum(s1, sh);
  s2 = bsum(s2, sh);
  float rl = 1.f / s1;
  float H  = (__logf(s1) - s2 * rl) / LOGT;

  if (tid < 64){
    float mw = wmaxr(ewin);
    mw = fmaxf(mw, 0.f);
    float t = ewin - mw;
    float w  = (tid < nb) ? __expf(t) : 0.f;
    float wt = (tid < nb) ? w * t     : 0.f;
    float z  = __expf(-mw);
    float s1w = wsum(w)  + (float)(TN - nb) * z;
    float s2w = wsum(wt) + (float)(TN - nb) * z * (-mw);
    if (tid == 0) Hwin[i] = (__logf(s1w) - s2w / s1w) / LOGT;
  }

  float ld = 0.f;
#pragma unroll
  for (int k = 0; k < 4; ++k){
    float e[4] = {v[k].x, v[k].y, v[k].z, v[k].w};
    float p[4];
#pragma unroll
    for (int q = 0; q < 4; ++q){
      p[q] = __expf(e[q] - mx) * rl;
      ld += log1pf(-p[q]);
    }
    bf16x4 pb = {(bf16)p[0], (bf16)p[1], (bf16)p[2], (bf16)p[3]};
    *(bf16x4*)&Pbf[(size_t)i * TN + (size_t)(k * 256 + tid) * 4] = pb;
  }
  ld = bsum(ld, sh);
  if (tid == 0){
    Hraw[i] = H;
    divh[i] = __expf(ld);
  }
}

// ---------------- L1 sums + normalize ----------------
__global__ __launch_bounds__(256) void k_sumvec(const float* __restrict__ Hraw,
                                                const float* __restrict__ divh,
                                                float* __restrict__ sums){
  __shared__ float sh[4];
  int tid = threadIdx.x;
  float a = 0.f, b = 0.f;
  for (int i = tid; i < TN; i += 256){ a += fabsf(Hraw[i]); b += fabsf(divh[i]); }
  a = bsum(a, sh);
  b = bsum(b, sh);
  if (tid == 0){ sums[0] = a; sums[1] = b; }
}
__global__ __launch_bounds__(256) void k_vecnorm(const float* __restrict__ Hraw,
                                                 const float* __restrict__ divh,
                                                 const float* __restrict__ sums,
                                                 float* __restrict__ entn,
                                                 float* __restrict__ divn){
  int i = blockIdx.x * 256 + threadIdx.x;
  if (i < TN){
    entn[i] = Hraw[i] / fmaxf(sums[0], EPSV);
    divn[i] = divh[i] / sums[1];
  }
}

// ---------------- dep_factor ----------------
__global__ __launch_bounds__(256) void k_dep(const float* __restrict__ xu,
                                             const float* __restrict__ stot,
                                             const float* __restrict__ cb,
                                             const bf16* __restrict__ Pbf,
                                             float* __restrict__ dep){
  __shared__ float xi[DI];
  __shared__ float sh[4];
  __shared__ float accs[4][3];
  int i = blockIdx.x, tid = threadIdx.x;
  float4 v = ((const float4*)(xu + (size_t)i * DI))[tid];
  ((float4*)xi)[tid] = v;
  float4 s4 = ((const float4*)stot)[tid];
  float4 c4 = ((const float4*)(cb + (size_t)i * DI))[tid];
  float pa = v.x*s4.x + v.y*s4.y + v.z*s4.z + v.w*s4.w;
  float pb = v.x*c4.x + v.y*c4.y + v.z*c4.z + v.w*c4.w;
  float sim_all    = bsum(pa, sh);
  float simatt_all = bsum(pb, sh);

  int b0 = (i / BSZ) * BSZ;
  int b1 = min(b0 + BSZ, TN);
  int nb = b1 - b0;
  int wid = tid >> 6, lane = tid & 63;
  float att_in = 0.f, sim_in = 0.f, simatt_in = 0.f;
  for (int j = b0 + wid; j < b1; j += 4){
    const float* xj = xu + (size_t)j * DI;
    float s = 0.f;
#pragma unroll
    for (int d = 0; d < 16; ++d) s += xi[d * 64 + lane] * xj[d * 64 + lane];
#pragma unroll
    for (int o = 32; o >= 1; o >>= 1) s += __shfl_xor(s, o);
    float att = (float)Pbf[(size_t)i * TN + j];
    att_in += att; sim_in += s; simatt_in += att * s;
  }
  if (lane == 0){ accs[wid][0] = att_in; accs[wid][1] = sim_in; accs[wid][2] = simatt_in; }
  __syncthreads();
  if (tid == 0){
    float a = 0.f, si = 0.f, sa = 0.f;
#pragma unroll
    for (int w = 0; w < 4; ++w){ a += accs[w][0]; si += accs[w][1]; sa += accs[w][2]; }
    float num = (1.f - a) - (simatt_all - sa);
    float den = (float)(TN - nb) - (sim_all - si);
    dep[i] = num / den;
  }
}

// ---------------- y_mid (bf16 out) ----------------
__global__ __launch_bounds__(256) void k_ymid(const bf16* __restrict__ Pbf,
                                              const float* __restrict__ dep,
                                              const float* __restrict__ V,
                                              bf16* __restrict__ ym){
  __shared__ float w[64];
  int i = blockIdx.x, tid = threadIdx.x;
  int b0 = (i / BSZ) * BSZ;
  int b1 = min(b0 + BSZ, TN);
  int nb = b1 - b0;
  if (tid < nb) w[tid] = (float)Pbf[(size_t)i * TN + b0 + tid] + dep[b0 + tid];
  __syncthreads();
  float4 a = {0.f, 0.f, 0.f, 0.f};
  for (int jj = 0; jj < nb; ++jj){
    float wv = w[jj];
    float4 vv = ((const float4*)(V + (size_t)(b0 + jj) * DI))[tid];
    a.x += wv * vv.x; a.y += wv * vv.y; a.z += wv * vv.z; a.w += wv * vv.w;
  }
  bf16x4 o = {(bf16)a.x, (bf16)a.y, (bf16)a.z, (bf16)a.w};
  *(bf16x4*)&ym[(size_t)i * DI + (size_t)tid * 4] = o;
}

// ---------------- fill att (reads P from ent-region scratch, writes att region) ----------------
__global__ __launch_bounds__(256) void k_fill_att(const bf16* __restrict__ Pbf,
                                                  const float* __restrict__ dep,
                                                  float* __restrict__ att){
  int i = blockIdx.x, tid = threadIdx.x;
  int b0 = (i / BSZ) * BSZ;
  int b1 = min(b0 + BSZ, TN);
#pragma unroll
  for (int g = 0; g < 4; ++g){
    int c = g * 1024 + tid * 4;
    size_t base = (size_t)i * TN + c;
    float4 av = {0.f, 0.f, 0.f, 0.f};
    if (c + 3 >= b0 && c < b1){
      float t2[4];
#pragma unroll
      for (int q = 0; q < 4; ++q){
        int j = c + q;
        t2[q] = (j >= b0 && j < b1) ? ((float)Pbf[(size_t)i * TN + j] + dep[j]) : 0.f;
      }
      av.x = t2[0]; av.y = t2[1]; av.z = t2[2]; av.w = t2[3];
    }
    *(float4*)&att[base] = av;
  }
}

// ---------------- fill ent/div (reads only ws vectors; clobbers all big scratch) ----------------
__global__ __launch_bounds__(256) void k_fill_entdiv(const float* __restrict__ Hw,
                                                     const float* __restrict__ divn,
                                                     float* __restrict__ ent,
                                                     float* __restrict__ div_){
  int i = blockIdx.x, tid = threadIdx.x;
#pragma unroll
  for (int g = 0; g < 4; ++g){
    int c = g * 1024 + tid * 4;
    size_t base = (size_t)i * TN + c;
    *(float4*)&ent[base]  = *(const float4*)&Hw[c];
    *(float4*)&div_[base] = *(const float4*)&divn[c];
  }
}

// ---------------- launcher ----------------
extern "C" void kernel_launch(void* const* d_in, const int* in_sizes, int n_in,
                              void* d_out, int out_size, void* d_ws, size_t ws_size,
                              hipStream_t stream){
  const float* x    = (const float*)d_in[0];
  const float* Wk   = (const float*)d_in[1];
  const float* Wq   = (const float*)d_in[2];
  const float* Wv   = (const float*)d_in[3];
  const float* Wout = (const float*)d_in[4];

  float* out     = (float*)d_out;
  float* y_out   = out;
  float* att_out = out + (size_t)TN * DI;
  float* ent_out = att_out + (size_t)TN * TN;
  float* div_out = ent_out + (size_t)TN * TN;
  float* E       = att_out;                 // E fp32 lives in att region until k_fill_att

  // scratch in ent+div regions (128 MB total). Offsets chosen so no two LIVE
  // buffers overlap; regions are overwritten by the two fill kernels at the end.
  char* S = (char*)ent_out;
  #define MB(x) ((size_t)(x) << 20)
  bf16* xhi  = (bf16*)(S + MB(0));    // dead after QKV GEMMs
  bf16* xlo  = (bf16*)(S + MB(8));
  bf16* Wqth = (bf16*)(S + MB(16));
  bf16* Wqtl = (bf16*)(S + MB(18));
  bf16* Wkth = (bf16*)(S + MB(20));
  bf16* Wktl = (bf16*)(S + MB(22));
  bf16* Wvth = (bf16*)(S + MB(24));
  bf16* Wot  = (bf16*)(S + MB(26));
  bf16* Qhi  = (bf16*)(S + MB(28));   // dead after E GEMM
  bf16* Qlo  = (bf16*)(S + MB(36));
  bf16* Khi  = (bf16*)(S + MB(44));
  bf16* Klo  = (bf16*)(S + MB(52));
  bf16* Pbf  = (bf16*)(S + MB(28));   // 32MB, overlays Q/K after E GEMM
  float* Vb  = (float*)(S + MB(60));  // 16MB
  float* xu  = (float*)(S + MB(76));  // 16MB
  bf16* xut  = (bf16*)(S + MB(92));   // 8MB
  float* cb  = (float*)(S + MB(0));   // 16MB, overlays xhi/xlo after QKV
  bf16* ym   = (bf16*)(S + MB(100));  // 8MB

  float* ws   = (float*)d_ws;         // ~236 KB of small vectors
  float* Hraw = ws;
  float* Hw   = Hraw + TN;
  float* divh = Hw + TN;
  float* dep  = divh + TN;
  float* entn = dep + TN;
  float* divn = entn + TN;
  float* part = divn + TN;
  float* stot = part + 32 * DI;
  float* sums = stot + DI;

  k_split<<<dim3(4096), 256, 0, stream>>>(x, xhi, xlo);
  k_rownorm<<<dim3(TN), 256, 0, stream>>>(x, xu);
  k_tr<true ><<<dim3(16,16), 256, 0, stream>>>(Wq, Wqth, Wqtl, DI, DI);
  k_tr<true ><<<dim3(16,16), 256, 0, stream>>>(Wk, Wkth, Wktl, DI, DI);
  k_tr<false><<<dim3(16,16), 256, 0, stream>>>(Wv, Wvth, nullptr, DI, DI);
  k_tr<false><<<dim3(16,16), 256, 0, stream>>>(Wout, Wot, nullptr, DI, DI);
  k_tr<false><<<dim3(16,64), 256, 0, stream>>>(xu, xut, nullptr, TN, DI);
  k_colsum1<<<dim3(4,32), 256, 0, stream>>>(xu, part);
  k_colsum2<<<dim3(4), 256, 0, stream>>>(part, stot);

  // Q, K: split 3-pass, bf16 hi/lo outputs
  k_mfma<3,1><<<dim3(8,32), 256, 0, stream>>>(xhi, xlo, Wqth, Wqtl, DI, DI, DI, DI,
                                              nullptr, Qhi, Qlo, nullptr, nullptr, nullptr);
  k_mfma<3,1><<<dim3(8,32), 256, 0, stream>>>(xhi, xlo, Wkth, Wktl, DI, DI, DI, DI,
                                              nullptr, Khi, Klo, nullptr, nullptr, nullptr);
  // V: plain, fp32 out
  k_mfma<1,0><<<dim3(8,32), 256, 0, stream>>>(xhi, nullptr, Wvth, nullptr, DI, DI, DI, DI,
                                              Vb, nullptr, nullptr, nullptr, nullptr, nullptr);
  // E = Q K^T: split 3-pass, fp32 out into att region
  k_mfma<3,0><<<dim3(32,32), 256, 0, stream>>>(Qhi, Qlo, Khi, Klo, DI, DI, TN, DI,
                                               E, nullptr, nullptr, nullptr, nullptr, nullptr);

  // E (att region) -> P bf16 (ent region, overlaying dead Q/K) + row stats
  k_rowstats<<<dim3(TN), 256, 0, stream>>>(E, Pbf, Hraw, Hw, divh);
  k_sumvec<<<dim3(1), 256, 0, stream>>>(Hraw, divh, sums);
  k_vecnorm<<<dim3(16), 256, 0, stream>>>(Hraw, divh, sums, entn, divn);

  // c = P @ xu
  k_mfma<1,0><<<dim3(8,32), 256, 0, stream>>>(Pbf, nullptr, xut, nullptr, TN, TN, DI, TN,
                                              cb, nullptr, nullptr, nullptr, nullptr, nullptr);

  k_dep<<<dim3(TN), 256, 0, stream>>>(xu, stot, cb, Pbf, dep);
  k_ymid<<<dim3(TN), 256, 0, stream>>>(Pbf, dep, Vb, ym);

  // y = ym @ Wout[:1024] + entn*Wout[1024] + dep*Wout[1025]
  k_mfma<1,2><<<dim3(8,32), 256, 0, stream>>>(ym, nullptr, Wot, nullptr, DI, DI, DI, DI,
                                              y_out, nullptr, nullptr, entn, dep,
                                              Wout + (size_t)DI * DI);

  k_fill_att<<<dim3(TN), 256, 0, stream>>>(Pbf, dep, att_out);
  k_fill_entdiv<<<dim3(TN), 256, 0, stream>>>(Hw, divn, ent_out, div_out);
}

// Round 4
// 497.849 us; speedup vs baseline: 3.1165x; 1.1152x over previous
//
#include <hip/hip_runtime.h>
#include <math.h>
#include <stdint.h>

#define TN   4096
#define DI   1024
#define BSZ  60
#define LOGT 8.317766166719343f
#define EPSV 1e-12f

typedef __bf16 bf16;
typedef bf16  bf16x4 __attribute__((ext_vector_type(4)));
typedef bf16  bf16x8 __attribute__((ext_vector_type(8)));
typedef float f32x4  __attribute__((ext_vector_type(4)));

#define AS1 __attribute__((address_space(1)))
#define AS3 __attribute__((address_space(3)))

__device__ __forceinline__ void gload16(const void* g, void* l){
  __builtin_amdgcn_global_load_lds((AS1 unsigned int*)(uintptr_t)g,
                                   (AS3 unsigned int*)(unsigned int)(uintptr_t)l,
                                   16, 0, 0);
}

// ---------------- reductions ----------------
__device__ __forceinline__ float wsum(float v){
#pragma unroll
  for (int o = 32; o >= 1; o >>= 1) v += __shfl_xor(v, o);
  return v;
}
__device__ __forceinline__ float wmaxr(float v){
#pragma unroll
  for (int o = 32; o >= 1; o >>= 1) v = fmaxf(v, __shfl_xor(v, o));
  return v;
}
__device__ __forceinline__ float bsum(float v, float* sh){
  v = wsum(v);
  if ((threadIdx.x & 63) == 0) sh[threadIdx.x >> 6] = v;
  __syncthreads();
  float r = sh[0] + sh[1] + sh[2] + sh[3];
  __syncthreads();
  return r;
}
__device__ __forceinline__ float bmaxr(float v, float* sh){
  v = wmaxr(v);
  if ((threadIdx.x & 63) == 0) sh[threadIdx.x >> 6] = v;
  __syncthreads();
  float r = fmaxf(fmaxf(sh[0], sh[1]), fmaxf(sh[2], sh[3]));
  __syncthreads();
  return r;
}

// ---------------- prep: xu = normalize(x); xhi/xlo = bf16 split of x ----------------
__global__ __launch_bounds__(256) void k_prep(const float* __restrict__ x,
                                              float* __restrict__ xu,
                                              bf16* __restrict__ xhi,
                                              bf16* __restrict__ xlo){
  __shared__ float sh[4];
  int r = blockIdx.x, tid = threadIdx.x;
  float4 v = ((const float4*)(x + (size_t)r * DI))[tid];
  float ss = v.x*v.x + v.y*v.y + v.z*v.z + v.w*v.w;
  ss = bsum(ss, sh);
  float inv = 1.f / fmaxf(sqrtf(ss), EPSV);
  float4 o = {v.x*inv, v.y*inv, v.z*inv, v.w*inv};
  ((float4*)(xu + (size_t)r * DI))[tid] = o;
  size_t idx = (size_t)r * 256 + tid;
  bf16 h0 = (bf16)v.x, h1 = (bf16)v.y, h2 = (bf16)v.z, h3 = (bf16)v.w;
  bf16x4 hv = {h0, h1, h2, h3};
  bf16x4 lv = {(bf16)(v.x-(float)h0), (bf16)(v.y-(float)h1),
               (bf16)(v.z-(float)h2), (bf16)(v.w-(float)h3)};
  ((bf16x4*)xhi)[idx] = hv;
  ((bf16x4*)xlo)[idx] = lv;
}

// ---------------- fused weight transposes ----------------
// z=0..2: W{q,k,v} -> Bqkv hi/lo at row offset z*DI.  z=3: Wout[:DI] -> Woth (hi only).
__global__ __launch_bounds__(256) void k_trw(const float* __restrict__ W0,
                                             const float* __restrict__ W1,
                                             const float* __restrict__ W2,
                                             const float* __restrict__ W3,
                                             bf16* __restrict__ bh,
                                             bf16* __restrict__ bl,
                                             bf16* __restrict__ woth){
  __shared__ float t[64][65];
  int z = blockIdx.z;
  const float* src = (z==0) ? W0 : (z==1) ? W1 : (z==2) ? W2 : W3;
  bf16* dh = (z < 3) ? bh + (size_t)z * DI * DI : woth;
  bf16* dl = (z < 3) ? bl + (size_t)z * DI * DI : nullptr;
  int c0 = blockIdx.x * 64, r0 = blockIdx.y * 64;
  int tid = threadIdx.x;
  int lr = tid >> 4, lc = (tid & 15) * 4;
#pragma unroll
  for (int p = 0; p < 4; ++p){
    int r = lr + p * 16;
    float4 v = *(const float4*)&src[(size_t)(r0 + r) * DI + c0 + lc];
    t[r][lc+0] = v.x; t[r][lc+1] = v.y; t[r][lc+2] = v.z; t[r][lc+3] = v.w;
  }
  __syncthreads();
#pragma unroll
  for (int p = 0; p < 4; ++p){
    int c = lr + p * 16;
    float v0 = t[lc+0][c], v1 = t[lc+1][c], v2 = t[lc+2][c], v3 = t[lc+3][c];
    bf16 h0 = (bf16)v0, h1 = (bf16)v1, h2 = (bf16)v2, h3 = (bf16)v3;
    bf16x4 hv = {h0, h1, h2, h3};
    *(bf16x4*)&dh[(size_t)(c0 + c) * DI + r0 + lc] = hv;
    if (dl){
      bf16x4 lv = {(bf16)(v0-(float)h0), (bf16)(v1-(float)h1),
                   (bf16)(v2-(float)h2), (bf16)(v3-(float)h3)};
      *(bf16x4*)&dl[(size_t)(c0 + c) * DI + r0 + lc] = lv;
    }
  }
}

// ---------------- transpose fp32 [R][C] -> bf16 [C][R] ----------------
__global__ __launch_bounds__(256) void k_trx(const float* __restrict__ in,
                                             bf16* __restrict__ outh,
                                             int R, int C){
  __shared__ float t[64][65];
  int c0 = blockIdx.x * 64, r0 = blockIdx.y * 64;
  int tid = threadIdx.x;
  int lr = tid >> 4, lc = (tid & 15) * 4;
#pragma unroll
  for (int p = 0; p < 4; ++p){
    int r = lr + p * 16;
    float4 v = *(const float4*)&in[(size_t)(r0 + r) * C + c0 + lc];
    t[r][lc+0] = v.x; t[r][lc+1] = v.y; t[r][lc+2] = v.z; t[r][lc+3] = v.w;
  }
  __syncthreads();
#pragma unroll
  for (int p = 0; p < 4; ++p){
    int c = lr + p * 16;
    bf16x4 hv = {(bf16)t[lc+0][c], (bf16)t[lc+1][c], (bf16)t[lc+2][c], (bf16)t[lc+3][c]};
    *(bf16x4*)&outh[(size_t)(c0 + c) * R + r0 + lc] = hv;
  }
}

// ---------------- column sums of xu ----------------
__global__ __launch_bounds__(256) void k_colsum1(const float* __restrict__ xu,
                                                 float* __restrict__ part){
  int c  = blockIdx.x * 256 + threadIdx.x;
  int r0 = blockIdx.y * 128;
  float s = 0.f;
  for (int r = r0; r < r0 + 128; ++r) s += xu[(size_t)r * DI + c];
  part[(size_t)blockIdx.y * DI + c] = s;
}
__global__ __launch_bounds__(256) void k_colsum2(const float* __restrict__ part,
                                                 float* __restrict__ stot){
  int c = blockIdx.x * 256 + threadIdx.x;
  float s = 0.f;
  for (int b = 0; b < 32; ++b) s += part[(size_t)b * DI + c];
  stot[c] = s;
}

// ---------------- MFMA GEMM: C[M,N] = A[M,K] * Bt[N,K]^T ----------------
// SPLIT: 1 = plain, 3 = hi/lo 3-pass.
// EPI: 0 = fp32 C
//      2 = fp32 C + (ev[row]/max(sums[0],eps))*W12[col] + dv[row]*W12[DI+col]
//      3 = QKV: cols<2048 -> bf16 hi/lo (Q or K); cols>=2048 -> fp32 C (V)
template<int SPLIT, int EPI>
__global__ __launch_bounds__(256) void k_mfma(
    const bf16* __restrict__ Ah, const bf16* __restrict__ Al,
    const bf16* __restrict__ Bh, const bf16* __restrict__ Bl,
    int lda, int ldb, int N, int K,
    float* __restrict__ C,
    bf16* __restrict__ Qh, bf16* __restrict__ Ql,
    bf16* __restrict__ Kh, bf16* __restrict__ Kl,
    const float* __restrict__ ev, const float* __restrict__ dv,
    const float* __restrict__ sums, const float* __restrict__ W12)
{
  constexpr int NT = (SPLIT == 3) ? 4 : 2;
  __shared__ alignas(16) bf16 lds[NT * 4096];
  bf16* sAh = lds;
  bf16* sBh = lds + 4096;
  bf16* sAl = lds + 8192;
  bf16* sBl = lds + 12288;

  const int tid = threadIdx.x;
  const int wid = tid >> 6;
  const int lane = tid & 63;
  const int row0 = blockIdx.y * 128, col0 = blockIdx.x * 128;
  const int wr = (wid >> 1) * 64, wc = (wid & 1) * 64;
  const int l15 = lane & 15, kb = lane >> 4;

  // staging: unit u (0..511) = 16B; row=u>>2, slot=u&3, src koff = slot ^ ((row>>1)&3)
  const int u0 = tid,       r0u = u0 >> 2, k0u = (u0 & 3) ^ ((r0u >> 1) & 3);
  const int u1 = tid + 256, r1u = u1 >> 2, k1u = (u1 & 3) ^ ((r1u >> 1) & 3);
  const int d0 = wid * 64 * 8;
  const int d1 = (256 + wid * 64) * 8;

  f32x4 acc[4][4];
  const f32x4 zero = {0.f, 0.f, 0.f, 0.f};
#pragma unroll
  for (int m = 0; m < 4; ++m)
#pragma unroll
    for (int n = 0; n < 4; ++n) acc[m][n] = zero;

  const bf16* pAh = Ah + (size_t)row0 * lda;
  const bf16* pBh = Bh + (size_t)col0 * ldb;
  const bf16* pAl = (SPLIT == 3) ? Al + (size_t)row0 * lda : nullptr;
  const bf16* pBl = (SPLIT == 3) ? Bl + (size_t)col0 * ldb : nullptr;

  for (int k0 = 0; k0 < K; k0 += 32){
    gload16(pAh + k0 + (size_t)r0u * lda + k0u * 8, sAh + d0);
    gload16(pAh + k0 + (size_t)r1u * lda + k1u * 8, sAh + d1);
    gload16(pBh + k0 + (size_t)r0u * ldb + k0u * 8, sBh + d0);
    gload16(pBh + k0 + (size_t)r1u * ldb + k1u * 8, sBh + d1);
    if constexpr (SPLIT == 3){
      gload16(pAl + k0 + (size_t)r0u * lda + k0u * 8, sAl + d0);
      gload16(pAl + k0 + (size_t)r1u * lda + k1u * 8, sAl + d1);
      gload16(pBl + k0 + (size_t)r0u * ldb + k0u * 8, sBl + d0);
      gload16(pBl + k0 + (size_t)r1u * ldb + k1u * 8, sBl + d1);
    }
    __syncthreads();

    bf16x8 bh[4], bl2[4];
#pragma unroll
    for (int n = 0; n < 4; ++n){
      int rr = wc + n * 16 + l15;
      int ss = kb ^ ((rr >> 1) & 3);
      bh[n] = *(const bf16x8*)(sBh + (rr * 4 + ss) * 8);
      if constexpr (SPLIT == 3) bl2[n] = *(const bf16x8*)(sBl + (rr * 4 + ss) * 8);
    }
#pragma unroll
    for (int m = 0; m < 4; ++m){
      int rr = wr + m * 16 + l15;
      int ss = kb ^ ((rr >> 1) & 3);
      bf16x8 ah = *(const bf16x8*)(sAh + (rr * 4 + ss) * 8);
      bf16x8 al2;
      if constexpr (SPLIT == 3) al2 = *(const bf16x8*)(sAl + (rr * 4 + ss) * 8);
#pragma unroll
      for (int n = 0; n < 4; ++n){
        acc[m][n] = __builtin_amdgcn_mfma_f32_16x16x32_bf16(ah, bh[n], acc[m][n], 0, 0, 0);
        if constexpr (SPLIT == 3){
          acc[m][n] = __builtin_amdgcn_mfma_f32_16x16x32_bf16(ah, bl2[n], acc[m][n], 0, 0, 0);
          acc[m][n] = __builtin_amdgcn_mfma_f32_16x16x32_bf16(al2, bh[n], acc[m][n], 0, 0, 0);
        }
      }
    }
    __syncthreads();
  }

  const int l4 = lane >> 4;
#pragma unroll
  for (int m = 0; m < 4; ++m){
#pragma unroll
    for (int n = 0; n < 4; ++n){
#pragma unroll
      for (int r = 0; r < 4; ++r){
        int row = row0 + wr + m * 16 + l4 * 4 + r;
        int col = col0 + wc + n * 16 + l15;
        float v = acc[m][n][r];
        if constexpr (EPI == 0){
          C[(size_t)row * N + col] = v;
        } else if constexpr (EPI == 2){
          float en = ev[row] / fmaxf(sums[0], EPSV);
          v += en * W12[col] + dv[row] * W12[DI + col];
          C[(size_t)row * N + col] = v;
        } else {  // EPI == 3 : QKV
          if (col0 < 2048){
            bf16* dh = (col0 < 1024) ? Qh : Kh;
            bf16* dl = (col0 < 1024) ? Ql : Kl;
            int cc = col & 1023;
            bf16 h = (bf16)v;
            dh[(size_t)row * DI + cc] = h;
            dl[(size_t)row * DI + cc] = (bf16)(v - (float)h);
          } else {
            C[(size_t)row * DI + (col - 2048)] = v;
          }
        }
      }
    }
  }
}

// ---------------- row stats over E -> P bf16 + Hraw/Hwin/divh ----------------
__global__ __launch_bounds__(256) void k_rowstats(const float* __restrict__ E,
                                                  bf16* __restrict__ Pbf,
                                                  float* __restrict__ Hraw,
                                                  float* __restrict__ Hwin,
                                                  float* __restrict__ divh){
  __shared__ float sh[4];
  int i = blockIdx.x, tid = threadIdx.x;
  const float4* row4 = (const float4*)(E + (size_t)i * TN);
  float4 v[4];
#pragma unroll
  for (int k = 0; k < 4; ++k) v[k] = row4[tid + k * 256];

  int b0 = (i / BSZ) * BSZ;
  int b1 = min(b0 + BSZ, TN);
  int nb = b1 - b0;
  float ewin = -3.4e38f;
  if (tid < 64 && tid < nb) ewin = E[(size_t)i * TN + b0 + tid];

  float mx = -3.4e38f;
#pragma unroll
  for (int k = 0; k < 4; ++k)
    mx = fmaxf(mx, fmaxf(fmaxf(v[k].x, v[k].y), fmaxf(v[k].z, v[k].w)));
  mx = bmaxr(mx, sh);

  float s1 = 0.f, s2 = 0.f;
#pragma unroll
  for (int k = 0; k < 4; ++k){
    float e[4] = {v[k].x, v[k].y, v[k].z, v[k].w};
#pragma unroll
    for (int q = 0; q < 4; ++q){
      float t = e[q] - mx; float w = __expf(t); s1 += w; s2 += w * t;
    }
  }
  s1 = bsum(s1, sh);
  s2 = bsum(s2, sh);
  float rl = 1.f / s1;
  float H  = (__logf(s1) - s2 * rl) / LOGT;

  if (tid < 64){
    float mw = wmaxr(ewin);
    mw = fmaxf(mw, 0.f);
    float t = ewin - mw;
    float w  = (tid < nb) ? __expf(t) : 0.f;
    float wt = (tid < nb) ? w * t     : 0.f;
    float z  = __expf(-mw);
    float s1w = wsum(w)  + (float)(TN - nb) * z;
    float s2w = wsum(wt) + (float)(TN - nb) * z * (-mw);
    if (tid == 0) Hwin[i] = (__logf(s1w) - s2w / s1w) / LOGT;
  }

  float ld = 0.f;
#pragma unroll
  for (int k = 0; k < 4; ++k){
    float e[4] = {v[k].x, v[k].y, v[k].z, v[k].w};
    float p[4];
#pragma unroll
    for (int q = 0; q < 4; ++q){
      p[q] = __expf(e[q] - mx) * rl;
      ld += log1pf(-p[q]);
    }
    bf16x4 pb = {(bf16)p[0], (bf16)p[1], (bf16)p[2], (bf16)p[3]};
    *(bf16x4*)&Pbf[(size_t)i * TN + (size_t)(k * 256 + tid) * 4] = pb;
  }
  ld = bsum(ld, sh);
  if (tid == 0){
    Hraw[i] = H;
    divh[i] = __expf(ld);
  }
}

// ---------------- L1 sums ----------------
__global__ __launch_bounds__(256) void k_sumvec(const float* __restrict__ Hraw,
                                                const float* __restrict__ divh,
                                                float* __restrict__ sums){
  __shared__ float sh[4];
  int tid = threadIdx.x;
  float a = 0.f, b = 0.f;
  for (int i = tid; i < TN; i += 256){ a += fabsf(Hraw[i]); b += fabsf(divh[i]); }
  a = bsum(a, sh);
  b = bsum(b, sh);
  if (tid == 0){ sums[0] = a; sums[1] = b; }
}

// ---------------- dep_factor ----------------
__global__ __launch_bounds__(256) void k_dep(const float* __restrict__ xu,
                                             const float* __restrict__ stot,
                                             const float* __restrict__ cb,
                                             const bf16* __restrict__ Pbf,
                                             float* __restrict__ dep){
  __shared__ float xi[DI];
  __shared__ float sh[4];
  __shared__ float accs[4][3];
  int i = blockIdx.x, tid = threadIdx.x;
  float4 v = ((const float4*)(xu + (size_t)i * DI))[tid];
  ((float4*)xi)[tid] = v;
  float4 s4 = ((const float4*)stot)[tid];
  float4 c4 = ((const float4*)(cb + (size_t)i * DI))[tid];
  float pa = v.x*s4.x + v.y*s4.y + v.z*s4.z + v.w*s4.w;
  float pb = v.x*c4.x + v.y*c4.y + v.z*c4.z + v.w*c4.w;
  float sim_all    = bsum(pa, sh);
  float simatt_all = bsum(pb, sh);

  int b0 = (i / BSZ) * BSZ;
  int b1 = min(b0 + BSZ, TN);
  int nb = b1 - b0;
  int wid = tid >> 6, lane = tid & 63;
  float att_in = 0.f, sim_in = 0.f, simatt_in = 0.f;
  for (int j = b0 + wid; j < b1; j += 4){
    const float* xj = xu + (size_t)j * DI;
    float s = 0.f;
#pragma unroll
    for (int d = 0; d < 16; ++d) s += xi[d * 64 + lane] * xj[d * 64 + lane];
#pragma unroll
    for (int o = 32; o >= 1; o >>= 1) s += __shfl_xor(s, o);
    float att = (float)Pbf[(size_t)i * TN + j];
    att_in += att; sim_in += s; simatt_in += att * s;
  }
  if (lane == 0){ accs[wid][0] = att_in; accs[wid][1] = sim_in; accs[wid][2] = simatt_in; }
  __syncthreads();
  if (tid == 0){
    float a = 0.f, si = 0.f, sa = 0.f;
#pragma unroll
    for (int w = 0; w < 4; ++w){ a += accs[w][0]; si += accs[w][1]; sa += accs[w][2]; }
    float num = (1.f - a) - (simatt_all - sa);
    float den = (float)(TN - nb) - (sim_all - si);
    dep[i] = num / den;
  }
}

// ---------------- epi: att row fill + y_mid, one block per row ----------------
__global__ __launch_bounds__(256) void k_epi(const bf16* __restrict__ Pbf,
                                             const float* __restrict__ dep,
                                             const float* __restrict__ V,
                                             float* __restrict__ att,
                                             bf16* __restrict__ ym){
  __shared__ float w[64];
  int i = blockIdx.x, tid = threadIdx.x;
  int b0 = (i / BSZ) * BSZ;
  int b1 = min(b0 + BSZ, TN);
  int nb = b1 - b0;
  if (tid < nb) w[tid] = (float)Pbf[(size_t)i * TN + b0 + tid] + dep[b0 + tid];
  __syncthreads();

#pragma unroll
  for (int g = 0; g < 4; ++g){
    int c = g * 1024 + tid * 4;
    size_t base = (size_t)i * TN + c;
    float4 av = {0.f, 0.f, 0.f, 0.f};
    if (c + 3 >= b0 && c < b1){
      float t2[4];
#pragma unroll
      for (int q = 0; q < 4; ++q){
        int j = c + q;
        t2[q] = (j >= b0 && j < b1) ? w[j - b0] : 0.f;
      }
      av.x = t2[0]; av.y = t2[1]; av.z = t2[2]; av.w = t2[3];
    }
    *(float4*)&att[base] = av;
  }

  float4 a = {0.f, 0.f, 0.f, 0.f};
  for (int jj = 0; jj < nb; ++jj){
    float wv = w[jj];
    float4 vv = ((const float4*)(V + (size_t)(b0 + jj) * DI))[tid];
    a.x += wv * vv.x; a.y += wv * vv.y; a.z += wv * vv.z; a.w += wv * vv.w;
  }
  bf16x4 o = {(bf16)a.x, (bf16)a.y, (bf16)a.z, (bf16)a.w};
  *(bf16x4*)&ym[(size_t)i * DI + (size_t)tid * 4] = o;
}

// ---------------- ent/div fill (runs LAST; clobbers all big scratch) ----------------
__global__ __launch_bounds__(256) void k_fill_entdiv(const float* __restrict__ Hw,
                                                     const float* __restrict__ divh,
                                                     const float* __restrict__ sums,
                                                     float* __restrict__ ent,
                                                     float* __restrict__ div_){
  int i = blockIdx.x, tid = threadIdx.x;
  float rs = 1.f / sums[1];
#pragma unroll
  for (int g = 0; g < 4; ++g){
    int c = g * 1024 + tid * 4;
    size_t base = (size_t)i * TN + c;
    float4 hv = *(const float4*)&Hw[c];
    float4 dv = *(const float4*)&divh[c];
    float4 dn = {dv.x*rs, dv.y*rs, dv.z*rs, dv.w*rs};
    *(float4*)&ent[base]  = hv;
    *(float4*)&div_[base] = dn;
  }
}

// ---------------- launcher ----------------
extern "C" void kernel_launch(void* const* d_in, const int* in_sizes, int n_in,
                              void* d_out, int out_size, void* d_ws, size_t ws_size,
                              hipStream_t stream){
  const float* x    = (const float*)d_in[0];
  const float* Wk   = (const float*)d_in[1];
  const float* Wq   = (const float*)d_in[2];
  const float* Wv   = (const float*)d_in[3];
  const float* Wout = (const float*)d_in[4];

  float* out     = (float*)d_out;
  float* y_out   = out;
  float* att_out = out + (size_t)TN * DI;
  float* ent_out = att_out + (size_t)TN * TN;
  float* div_out = ent_out + (size_t)TN * TN;
  float* E       = att_out;               // E fp32 in att region until k_epi

  // scratch in ent+div regions (128 MB). Lifetime-disjoint layout; both regions
  // are overwritten only by k_fill_entdiv at the very end.
  char* S = (char*)ent_out;
  #define MB(x) ((size_t)(x) << 20)
  bf16* xhi  = (bf16*)(S + MB(0));    // 8MB, dead after QKV
  bf16* xlo  = (bf16*)(S + MB(8));    // 8MB, dead after QKV
  bf16* Bqh  = (bf16*)(S + MB(16));   // 6MB [3072][1024], dead after QKV
  bf16* Bql  = (bf16*)(S + MB(22));   // 6MB
  bf16* Woth = (bf16*)(S + MB(28));   // 2MB, read by final GEMM
  bf16* xut  = (bf16*)(S + MB(30));   // 8MB, read by c-GEMM
  bf16* Qhi  = (bf16*)(S + MB(38));   // 8MB, dead after E
  bf16* Qlo  = (bf16*)(S + MB(46));   // 8MB
  bf16* Khi  = (bf16*)(S + MB(54));   // 8MB
  bf16* Klo  = (bf16*)(S + MB(62));   // 8MB
  bf16* Pbf  = (bf16*)(S + MB(38));   // 32MB, overlays Q/K after E
  float* Vb  = (float*)(S + MB(70));  // 16MB, read until k_epi
  float* xu  = (float*)(S + MB(86));  // 16MB, read until k_dep
  float* cb  = (float*)(S + MB(0));   // 16MB, overlays xhi/xlo after QKV
  bf16* ym   = (bf16*)(S + MB(102));  // 8MB, written k_epi, read final GEMM

  float* ws   = (float*)d_ws;
  float* Hraw = ws;
  float* Hw   = Hraw + TN;
  float* divh = Hw + TN;
  float* dep  = divh + TN;
  float* part = dep + TN;           // 32*DI
  float* stot = part + 32 * DI;     // DI
  float* sums = stot + DI;          // 2

  k_prep<<<dim3(TN), 256, 0, stream>>>(x, xu, xhi, xlo);
  k_trw<<<dim3(16,16,4), 256, 0, stream>>>(Wq, Wk, Wv, Wout, Bqh, Bql, Woth);
  k_trx<<<dim3(16,64), 256, 0, stream>>>(xu, xut, TN, DI);
  k_colsum1<<<dim3(4,32), 256, 0, stream>>>(xu, part);
  k_colsum2<<<dim3(4), 256, 0, stream>>>(part, stot);

  // fused QKV: split-3, N=3072; Q,K -> bf16 hi/lo; V -> fp32
  k_mfma<3,3><<<dim3(24,32), 256, 0, stream>>>(xhi, xlo, Bqh, Bql, DI, DI, 3072, DI,
                                               Vb, Qhi, Qlo, Khi, Klo,
                                               nullptr, nullptr, nullptr, nullptr);
  // E = Q K^T (split-3) into att region
  k_mfma<3,0><<<dim3(32,32), 256, 0, stream>>>(Qhi, Qlo, Khi, Klo, DI, DI, TN, DI,
                                               E, nullptr, nullptr, nullptr, nullptr,
                                               nullptr, nullptr, nullptr, nullptr);

  k_rowstats<<<dim3(TN), 256, 0, stream>>>(E, Pbf, Hraw, Hw, divh);
  k_sumvec<<<dim3(1), 256, 0, stream>>>(Hraw, divh, sums);

  // c = P @ xu
  k_mfma<1,0><<<dim3(8,32), 256, 0, stream>>>(Pbf, nullptr, xut, nullptr, TN, TN, DI, TN,
                                              cb, nullptr, nullptr, nullptr, nullptr,
                                              nullptr, nullptr, nullptr, nullptr);

  k_dep<<<dim3(TN), 256, 0, stream>>>(xu, stot, cb, Pbf, dep);
  k_epi<<<dim3(TN), 256, 0, stream>>>(Pbf, dep, Vb, att_out, ym);

  // y = ym @ Wout[:DI] + (Hraw/|Hraw|1)*Wout[DI] + dep*Wout[DI+1]
  k_mfma<1,2><<<dim3(8,32), 256, 0, stream>>>(ym, nullptr, Woth, nullptr, DI, DI, DI, DI,
                                              y_out, nullptr, nullptr, nullptr, nullptr,
                                              Hraw, dep, sums, Wout + (size_t)DI * DI);

  k_fill_entdiv<<<dim3(TN), 256, 0, stream>>>(Hw, divh, sums, ent_out, div_out);
}